// Round 1
// baseline (932.191 us; speedup 1.0000x reference)
//
#include <hip/hip_runtime.h>
#include <math.h>

typedef unsigned short u16;
typedef __attribute__((ext_vector_type(4))) unsigned short u16x4;
typedef __attribute__((ext_vector_type(8))) short s16x8;
typedef __attribute__((ext_vector_type(4))) float f32x4;
typedef __attribute__((ext_vector_type(4))) float f4v;

#define DEVI static __device__ __forceinline__

DEVI u16 f2bf(float f) {
  union { float f; unsigned u; } c; c.f = f;
  return (u16)((c.u + 0x7FFFu + ((c.u >> 16) & 1u)) >> 16);
}
DEVI float bf2f(u16 h) {
  union { unsigned u; float f; } c; c.u = ((unsigned)h) << 16;
  return c.f;
}

DEVI void load_lds16(const void* g, void* l) {
  __builtin_amdgcn_global_load_lds(
      (const __attribute__((address_space(1))) void*)g,
      (__attribute__((address_space(3))) void*)l, 16, 0, 0);
}

// ------------------------- small kernels -------------------------

__global__ __launch_bounds__(256) void cast_bf4_kernel(
    const float* __restrict__ in, u16* __restrict__ out, int n4) {
  int i = blockIdx.x * 256 + threadIdx.x;
  if (i >= n4) return;
  f4v f = ((const f4v*)in)[i];
  u16x4 o;
  o[0] = f2bf(f[0]); o[1] = f2bf(f[1]); o[2] = f2bf(f[2]); o[3] = f2bf(f[3]);
  ((u16x4*)out)[i] = o;
}

// per row (b,n): tq=tanh(q)*.499+.5 ; qp=clip(tq/(sum+1e-8),1e-8)
// A = bf16(qp - kp), Bm = bf16(log qp - log kp)
__global__ __launch_bounds__(256) void prob_kernel(
    const float* __restrict__ q, const float* __restrict__ k,
    u16* __restrict__ A, u16* __restrict__ Bm) {
  const int D = 1024;
  size_t row = blockIdx.x;
  int t = threadIdx.x;
  f4v qv = ((const f4v*)(q + row * D))[t];
  f4v kv = ((const f4v*)(k + row * D))[t];
  float tq[4], tk[4];
  float sq = 0.f, sk = 0.f;
#pragma unroll
  for (int i = 0; i < 4; i++) {
    tq[i] = tanhf(qv[i]) * 0.499f + 0.5f;
    tk[i] = tanhf(kv[i]) * 0.499f + 0.5f;
    sq += tq[i]; sk += tk[i];
  }
#pragma unroll
  for (int off = 32; off > 0; off >>= 1) {
    sq += __shfl_xor(sq, off);
    sk += __shfl_xor(sk, off);
  }
  __shared__ float sbq[4], sbk[4];
  int lane = t & 63, w = t >> 6;
  if (lane == 0) { sbq[w] = sq; sbk[w] = sk; }
  __syncthreads();
  sq = sbq[0] + sbq[1] + sbq[2] + sbq[3];
  sk = sbk[0] + sbk[1] + sbk[2] + sbk[3];
  float iq = 1.0f / (sq + 1e-8f), ik = 1.0f / (sk + 1e-8f);
  u16x4 av, bv;
#pragma unroll
  for (int i = 0; i < 4; i++) {
    float qp = fmaxf(tq[i] * iq, 1e-8f);
    float kp = fmaxf(tk[i] * ik, 1e-8f);
    av[i] = f2bf(qp - kp);
    bv[i] = f2bf(logf(qp) - logf(kp));
  }
  ((u16x4*)(A + row * D))[t] = av;
  ((u16x4*)(Bm + row * D))[t] = bv;
}

// Vt[b][d][n] = bf16(v[b][n][d])
__global__ __launch_bounds__(256) void transpose_v_kernel(
    const float* __restrict__ v, u16* __restrict__ Vt) {
  const int N = 2048, D = 1024;
  __shared__ float tile[32][33];
  int b = blockIdx.z;
  int d0 = blockIdx.x * 32, n0 = blockIdx.y * 32;
  int tx = threadIdx.x & 31, ty = threadIdx.x >> 5;  // ty 0..7
  const float* vb = v + (size_t)b * N * D;
  u16* vtb = Vt + (size_t)b * N * D;
#pragma unroll
  for (int i = 0; i < 4; i++)
    tile[ty + i * 8][tx] = vb[(size_t)(n0 + ty + i * 8) * D + d0 + tx];
  __syncthreads();
#pragma unroll
  for (int i = 0; i < 4; i++)
    vtb[(size_t)(d0 + ty + i * 8) * N + n0 + tx] = f2bf(tile[tx][ty + i * 8]);
}

// in-place row softmax on bf16 rows of length 2048
__global__ __launch_bounds__(256) void softmax_rows_kernel(u16* __restrict__ S) {
  const int NN = 2048;
  size_t row = blockIdx.x;
  u16* r = S + row * NN;
  int t = threadIdx.x;
  s16x8 vv = ((const s16x8*)r)[t];
  float x[8];
  float mx = -1e30f;
#pragma unroll
  for (int i = 0; i < 8; i++) { x[i] = bf2f((u16)vv[i]); mx = fmaxf(mx, x[i]); }
#pragma unroll
  for (int off = 32; off > 0; off >>= 1) mx = fmaxf(mx, __shfl_xor(mx, off));
  __shared__ float sm[4], ss[4];
  int lane = t & 63, w = t >> 6;
  if (lane == 0) sm[w] = mx;
  __syncthreads();
  mx = fmaxf(fmaxf(sm[0], sm[1]), fmaxf(sm[2], sm[3]));
  float sum = 0.f;
#pragma unroll
  for (int i = 0; i < 8; i++) { x[i] = expf(x[i] - mx); sum += x[i]; }
#pragma unroll
  for (int off = 32; off > 0; off >>= 1) sum += __shfl_xor(sum, off);
  if (lane == 0) ss[w] = sum;
  __syncthreads();
  float inv = 1.0f / (ss[0] + ss[1] + ss[2] + ss[3]);
  s16x8 ov;
#pragma unroll
  for (int i = 0; i < 8; i++) ov[i] = (short)f2bf(x[i] * inv);
  ((s16x8*)r)[t] = ov;
}

// LN over rows of 1024 f32. OUT_BF16=1 -> bf16 out, else f32 out (in-place ok)
template <int OUT_BF16>
__global__ __launch_bounds__(256) void layernorm_rows_kernel(
    const float* __restrict__ in, void* __restrict__ outp,
    const float* __restrict__ g, const float* __restrict__ bia) {
  const int D = 1024;
  size_t row = blockIdx.x;
  int t = threadIdx.x;
  f4v xv = ((const f4v*)(in + row * D))[t];
  float s = xv[0] + xv[1] + xv[2] + xv[3];
  float s2 = xv[0] * xv[0] + xv[1] * xv[1] + xv[2] * xv[2] + xv[3] * xv[3];
#pragma unroll
  for (int off = 32; off > 0; off >>= 1) {
    s += __shfl_xor(s, off);
    s2 += __shfl_xor(s2, off);
  }
  __shared__ float sa[4], sb[4];
  int lane = t & 63, w = t >> 6;
  if (lane == 0) { sa[w] = s; sb[w] = s2; }
  __syncthreads();
  s = sa[0] + sa[1] + sa[2] + sa[3];
  s2 = sb[0] + sb[1] + sb[2] + sb[3];
  float mean = s * (1.0f / D);
  float var = s2 * (1.0f / D) - mean * mean;
  float rs = rsqrtf(var + 1e-5f);
  f4v gv = ((const f4v*)g)[t];
  f4v bv = ((const f4v*)bia)[t];
  float y[4];
#pragma unroll
  for (int i = 0; i < 4; i++) y[i] = (xv[i] - mean) * rs * gv[i] + bv[i];
  if (OUT_BF16) {
    u16x4 o; o[0] = f2bf(y[0]); o[1] = f2bf(y[1]); o[2] = f2bf(y[2]); o[3] = f2bf(y[3]);
    ((u16x4*)outp)[row * (D / 4) + t] = o;
  } else {
    f4v o; o[0] = y[0]; o[1] = y[1]; o[2] = y[2]; o[3] = y[3];
    ((f4v*)outp)[row * (D / 4) + t] = o;
  }
}

// ------------------------- generic NT GEMM -------------------------
// C[i][j] = sum_k A[i][k] * Bmat[j][k]    (A: [M,K] bf16, Bmat: [Nc,K] bf16)
// EPI 0: C = bf16(acc*scale)
// EPI 1: C = bf16(aux1[ci] - acc)              (aux1 batched f32)
// EPI 2: C = f32(acc + aux2[col] + aux1[ci])   (aux1 flat f32)
// EPI 3: C = bf16(gelu_exact(acc + aux2[col]))
template <int EPI>
__global__ __launch_bounds__(256) void gemm_nt_kernel(
    const u16* __restrict__ Ab, const u16* __restrict__ Bb,
    void* __restrict__ Cout,
    const float* __restrict__ aux1, const float* __restrict__ aux2,
    int M, int Nc, int K,
    long sA, long sB, long sC, long sAux1, float scale) {
  __shared__ u16 As[128 * 64];
  __shared__ u16 Bs[128 * 64];
  int bz = blockIdx.z;
  const u16* Ap = Ab + (size_t)bz * sA;
  const u16* Bp = Bb + (size_t)bz * sB;
  int m0 = blockIdx.x * 128, n0 = blockIdx.y * 128;
  int t = threadIdx.x, w = t >> 6, l = t & 63;
  int wr = w >> 1, wc = w & 1;

  f32x4 acc[4][4];
#pragma unroll
  for (int m = 0; m < 4; m++)
#pragma unroll
    for (int n = 0; n < 4; n++) acc[m][n] = (f32x4){0.f, 0.f, 0.f, 0.f};

  int lrow = l >> 3, lcol = (l & 7) * 8;  // staging: lane -> (row-in-chunk, col8)

  for (int k0 = 0; k0 < K; k0 += 64) {
#pragma unroll
    for (int it = 0; it < 4; it++) {
      int chunk = it * 4 + w;
      int row = chunk * 8 + lrow;
      const u16* ga = Ap + (size_t)(m0 + row) * K + k0 + lcol;
      const u16* gb = Bp + (size_t)(n0 + row) * K + k0 + lcol;
      load_lds16(ga, As + chunk * 512);
      load_lds16(gb, Bs + chunk * 512);
    }
    __syncthreads();
#pragma unroll
    for (int kk = 0; kk < 2; kk++) {
      int colo = kk * 32 + (l >> 4) * 8;
      s16x8 af[4], bf[4];
#pragma unroll
      for (int m = 0; m < 4; m++)
        af[m] = *(const s16x8*)&As[(size_t)(wr * 64 + m * 16 + (l & 15)) * 64 + colo];
#pragma unroll
      for (int n = 0; n < 4; n++)
        bf[n] = *(const s16x8*)&Bs[(size_t)(wc * 64 + n * 16 + (l & 15)) * 64 + colo];
#pragma unroll
      for (int m = 0; m < 4; m++)
#pragma unroll
        for (int n = 0; n < 4; n++)
          acc[m][n] = __builtin_amdgcn_mfma_f32_16x16x32_bf16(af[m], bf[n], acc[m][n], 0, 0, 0);
    }
    __syncthreads();
  }

  int fr = l & 15, fq = l >> 4;
#pragma unroll
  for (int m = 0; m < 4; m++) {
#pragma unroll
    for (int n = 0; n < 4; n++) {
#pragma unroll
      for (int r = 0; r < 4; r++) {
        int grow = m0 + wr * 64 + m * 16 + fq * 4 + r;
        int gcol = n0 + wc * 64 + n * 16 + fr;
        float a = acc[m][n][r];
        size_t ci = (size_t)grow * Nc + gcol;
        if (EPI == 0) {
          ((u16*)Cout)[(size_t)bz * sC + ci] = f2bf(a * scale);
        } else if (EPI == 1) {
          float vv = aux1[(size_t)bz * sAux1 + ci];
          ((u16*)Cout)[(size_t)bz * sC + ci] = f2bf(vv - a);
        } else if (EPI == 2) {
          ((float*)Cout)[ci] = a + aux2[gcol] + aux1[ci];
        } else {  // EPI == 3
          float x = a + aux2[gcol];
          float gl = 0.5f * x * (1.0f + erff(x * 0.70710678118654752f));
          ((u16*)Cout)[ci] = f2bf(gl);
        }
      }
    }
  }
}

// ------------------------- launch -------------------------

extern "C" void kernel_launch(void* const* d_in, const int* in_sizes, int n_in,
                              void* d_out, int out_size, void* d_ws, size_t ws_size,
                              hipStream_t stream) {
  const float* q      = (const float*)d_in[0];
  const float* k      = (const float*)d_in[1];
  const float* v      = (const float*)d_in[2];
  const float* W_diff = (const float*)d_in[3];
  const float* b_diff = (const float*)d_in[4];
  const float* ln_g   = (const float*)d_in[5];
  const float* ln_b   = (const float*)d_in[6];
  const float* W1     = (const float*)d_in[7];
  const float* b1     = (const float*)d_in[8];
  const float* W2     = (const float*)d_in[9];
  const float* b2     = (const float*)d_in[10];

  const int B = 8, N = 2048, D = 1024, H = 4096;
  char* ws = (char*)d_ws;
  // lifetimes: A,Bm dead after GEMM1; S dead after GEMM2; X dead after GEMM3;
  // Vt dead after GEMM2; h live for GEMM4; G (134MB) aliases [0,134M).
  u16* A   = (u16*)(ws + 0);            // 33.5M
  u16* Bm  = (u16*)(ws + 33554432);     // 33.5M
  u16* X   = (u16*)(ws + 33554432);     // reuses Bm after GEMM1
  u16* Vt  = (u16*)(ws + 67108864);     // 33.5M
  u16* S   = (u16*)(ws + 100663296);    // 67M  (attn scores)
  u16* Hbf = (u16*)(ws + 134217728);    // 33.5M (post-LN activations)
  u16* Wd  = (u16*)(ws + 167772160);    // 2M
  u16* W1b = (u16*)(ws + 169869312);    // 8M
  u16* W2b = (u16*)(ws + 178257920);    // 8M  -> total 186646528 bytes
  u16* G   = (u16*)(ws + 0);            // 134M gelu hidden, aliases A/X/Vt/S-low
  float* out = (float*)d_out;           // also holds f_diff between GEMM3..GEMM5

  // weights -> bf16
  cast_bf4_kernel<<<(D * D / 4) / 256, 256, 0, stream>>>(W_diff, Wd, D * D / 4);
  cast_bf4_kernel<<<(H * D / 4) / 256, 256, 0, stream>>>(W1, W1b, H * D / 4);
  cast_bf4_kernel<<<(D * H / 4) / 256, 256, 0, stream>>>(W2, W2b, D * H / 4);

  // A = qp-kp, Bm = log qp - log kp
  prob_kernel<<<B * N, 256, 0, stream>>>(q, k, A, Bm);
  // Vt = v^T (bf16)
  transpose_v_kernel<<<dim3(D / 32, N / 32, B), 256, 0, stream>>>(v, Vt);

  // GEMM1: S = bf16(-(A @ Bm^T) / 32)
  gemm_nt_kernel<0><<<dim3(16, 16, 8), 256, 0, stream>>>(
      A, Bm, S, nullptr, nullptr, N, N, D,
      (long)N * D, (long)N * D, (long)N * N, 0, -0.03125f);

  // softmax rows (in place)
  softmax_rows_kernel<<<B * N, 256, 0, stream>>>(S);

  // GEMM2: X = bf16(v - attn @ v)   (B-operand = Vt)
  gemm_nt_kernel<1><<<dim3(16, 8, 8), 256, 0, stream>>>(
      S, Vt, X, v, nullptr, N, D, N,
      (long)N * N, (long)D * N, (long)N * D, (long)N * D, 1.0f);

  // GEMM3: f_diff = X @ Wd^T + b_diff + q   -> d_out (f32)
  gemm_nt_kernel<2><<<dim3(128, 8, 1), 256, 0, stream>>>(
      X, Wd, out, q, b_diff, B * N, D, D, 0, 0, 0, 0, 1.0f);

  // h = bf16(LN(f_diff))
  layernorm_rows_kernel<1><<<B * N, 256, 0, stream>>>(out, Hbf, ln_g, ln_b);

  // GEMM4: G = bf16(gelu(h @ W1^T + b1))
  gemm_nt_kernel<3><<<dim3(128, 32, 1), 256, 0, stream>>>(
      Hbf, W1b, G, nullptr, b1, B * N, H, D, 0, 0, 0, 0, 1.0f);

  // GEMM5: out = G @ W2^T + b2 + f_diff   (f_diff read from d_out, exclusive per-element)
  gemm_nt_kernel<2><<<dim3(128, 8, 1), 256, 0, stream>>>(
      G, W2b, out, out, b2, B * N, D, H, 0, 0, 0, 0, 1.0f);

  // final LN in place on d_out
  layernorm_rows_kernel<0><<<B * N, 256, 0, stream>>>(out, out, ln_g, ln_b);
}

// Round 3
// 657.559 us; speedup vs baseline: 1.4177x; 1.4177x over previous
//
#include <hip/hip_runtime.h>
#include <math.h>

typedef unsigned short u16;
typedef __attribute__((ext_vector_type(4))) unsigned short u16x4;
typedef __attribute__((ext_vector_type(8))) short s16x8;
typedef __attribute__((ext_vector_type(4))) float f32x4;
typedef __attribute__((ext_vector_type(4))) float f4v;

#define DEVI static __device__ __forceinline__

DEVI u16 f2bf(float f) {
  union { float f; unsigned u; } c; c.f = f;
  return (u16)((c.u + 0x7FFFu + ((c.u >> 16) & 1u)) >> 16);
}
DEVI float bf2f(u16 h) {
  union { unsigned u; float f; } c; c.u = ((unsigned)h) << 16;
  return c.f;
}

DEVI void load_lds16(const void* g, void* l) {
  __builtin_amdgcn_global_load_lds(
      (const __attribute__((address_space(1))) void*)g,
      (__attribute__((address_space(3))) void*)l, 16, 0, 0);
}

#define BAR_VM6() asm volatile("s_waitcnt vmcnt(6)\n\ts_barrier" ::: "memory")
#define BAR_VM4() asm volatile("s_waitcnt vmcnt(4)\n\ts_barrier" ::: "memory")
#define BAR_VM2() asm volatile("s_waitcnt vmcnt(2)\n\ts_barrier" ::: "memory")
#define BAR_VM0() asm volatile("s_waitcnt vmcnt(0)\n\ts_barrier" ::: "memory")
#define BAR_PLAIN() asm volatile("s_barrier" ::: "memory")

// ------------------------- small kernels -------------------------

__global__ __launch_bounds__(256) void cast_bf4_kernel(
    const float* __restrict__ in, u16* __restrict__ out, int n4) {
  int i = blockIdx.x * 256 + threadIdx.x;
  if (i >= n4) return;
  f4v f = ((const f4v*)in)[i];
  u16x4 o;
  o[0] = f2bf(f[0]); o[1] = f2bf(f[1]); o[2] = f2bf(f[2]); o[3] = f2bf(f[3]);
  ((u16x4*)out)[i] = o;
}

__global__ __launch_bounds__(256) void prob_kernel(
    const float* __restrict__ q, const float* __restrict__ k,
    u16* __restrict__ A, u16* __restrict__ Bm) {
  const int D = 1024;
  size_t row = blockIdx.x;
  int t = threadIdx.x;
  f4v qv = ((const f4v*)(q + row * D))[t];
  f4v kv = ((const f4v*)(k + row * D))[t];
  float tq[4], tk[4];
  float sq = 0.f, sk = 0.f;
#pragma unroll
  for (int i = 0; i < 4; i++) {
    tq[i] = tanhf(qv[i]) * 0.499f + 0.5f;
    tk[i] = tanhf(kv[i]) * 0.499f + 0.5f;
    sq += tq[i]; sk += tk[i];
  }
#pragma unroll
  for (int off = 32; off > 0; off >>= 1) {
    sq += __shfl_xor(sq, off);
    sk += __shfl_xor(sk, off);
  }
  __shared__ float sbq[4], sbk[4];
  int lane = t & 63, w = t >> 6;
  if (lane == 0) { sbq[w] = sq; sbk[w] = sk; }
  __syncthreads();
  sq = sbq[0] + sbq[1] + sbq[2] + sbq[3];
  sk = sbk[0] + sbk[1] + sbk[2] + sbk[3];
  float iq = 1.0f / (sq + 1e-8f), ik = 1.0f / (sk + 1e-8f);
  u16x4 av, bv;
#pragma unroll
  for (int i = 0; i < 4; i++) {
    float qp = fmaxf(tq[i] * iq, 1e-8f);
    float kp = fmaxf(tk[i] * ik, 1e-8f);
    av[i] = f2bf(qp - kp);
    bv[i] = f2bf(logf(qp) - logf(kp));
  }
  ((u16x4*)(A + row * D))[t] = av;
  ((u16x4*)(Bm + row * D))[t] = bv;
}

__global__ __launch_bounds__(256) void transpose_v_kernel(
    const float* __restrict__ v, u16* __restrict__ Vt) {
  const int N = 2048, D = 1024;
  __shared__ float tile[32][33];
  int b = blockIdx.z;
  int d0 = blockIdx.x * 32, n0 = blockIdx.y * 32;
  int tx = threadIdx.x & 31, ty = threadIdx.x >> 5;
  const float* vb = v + (size_t)b * N * D;
  u16* vtb = Vt + (size_t)b * N * D;
#pragma unroll
  for (int i = 0; i < 4; i++)
    tile[ty + i * 8][tx] = vb[(size_t)(n0 + ty + i * 8) * D + d0 + tx];
  __syncthreads();
#pragma unroll
  for (int i = 0; i < 4; i++)
    vtb[(size_t)(d0 + ty + i * 8) * N + n0 + tx] = f2bf(tile[tx][ty + i * 8]);
}

__global__ __launch_bounds__(256) void softmax_rows_kernel(u16* __restrict__ S) {
  const int NN = 2048;
  size_t row = blockIdx.x;
  u16* r = S + row * NN;
  int t = threadIdx.x;
  s16x8 vv = ((const s16x8*)r)[t];
  float x[8];
  float mx = -1e30f;
#pragma unroll
  for (int i = 0; i < 8; i++) { x[i] = bf2f((u16)vv[i]); mx = fmaxf(mx, x[i]); }
#pragma unroll
  for (int off = 32; off > 0; off >>= 1) mx = fmaxf(mx, __shfl_xor(mx, off));
  __shared__ float sm[4], ss[4];
  int lane = t & 63, w = t >> 6;
  if (lane == 0) sm[w] = mx;
  __syncthreads();
  mx = fmaxf(fmaxf(sm[0], sm[1]), fmaxf(sm[2], sm[3]));
  float sum = 0.f;
#pragma unroll
  for (int i = 0; i < 8; i++) { x[i] = expf(x[i] - mx); sum += x[i]; }
#pragma unroll
  for (int off = 32; off > 0; off >>= 1) sum += __shfl_xor(sum, off);
  if (lane == 0) ss[w] = sum;
  __syncthreads();
  float inv = 1.0f / (ss[0] + ss[1] + ss[2] + ss[3]);
  s16x8 ov;
#pragma unroll
  for (int i = 0; i < 8; i++) ov[i] = (short)f2bf(x[i] * inv);
  ((s16x8*)r)[t] = ov;
}

template <int OUT_BF16>
__global__ __launch_bounds__(256) void layernorm_rows_kernel(
    const float* __restrict__ in, void* __restrict__ outp,
    const float* __restrict__ g, const float* __restrict__ bia) {
  const int D = 1024;
  size_t row = blockIdx.x;
  int t = threadIdx.x;
  f4v xv = ((const f4v*)(in + row * D))[t];
  float s = xv[0] + xv[1] + xv[2] + xv[3];
  float s2 = xv[0] * xv[0] + xv[1] * xv[1] + xv[2] * xv[2] + xv[3] * xv[3];
#pragma unroll
  for (int off = 32; off > 0; off >>= 1) {
    s += __shfl_xor(s, off);
    s2 += __shfl_xor(s2, off);
  }
  __shared__ float sa[4], sb[4];
  int lane = t & 63, w = t >> 6;
  if (lane == 0) { sa[w] = s; sb[w] = s2; }
  __syncthreads();
  s = sa[0] + sa[1] + sa[2] + sa[3];
  s2 = sb[0] + sb[1] + sb[2] + sb[3];
  float mean = s * (1.0f / D);
  float var = s2 * (1.0f / D) - mean * mean;
  float rs = rsqrtf(var + 1e-5f);
  f4v gv = ((const f4v*)g)[t];
  f4v bv = ((const f4v*)bia)[t];
  float y[4];
#pragma unroll
  for (int i = 0; i < 4; i++) y[i] = (xv[i] - mean) * rs * gv[i] + bv[i];
  if (OUT_BF16) {
    u16x4 o; o[0] = f2bf(y[0]); o[1] = f2bf(y[1]); o[2] = f2bf(y[2]); o[3] = f2bf(y[3]);
    ((u16x4*)outp)[row * (D / 4) + t] = o;
  } else {
    f4v o; o[0] = y[0]; o[1] = y[1]; o[2] = y[2]; o[3] = y[3];
    ((f4v*)outp)[row * (D / 4) + t] = o;
  }
}

// --------------- 8-phase 256x256 NT GEMM (T1+T2+T3+T4+T5) ---------------
// C[i][j] = sum_k A[i][k]*B[j][k]. A:[M,K] bf16, B:[Nc,K] bf16. M,Nc %256==0,
// K%128==0, grid 1-D = batch*(M/256)*(Nc/256), %8==0.
// LDS: A [slot2][half2][128r][64c] u16, B same at +32768 u16. 128 KiB.
// Swizzle: 16B-chunk idx (3b) XOR (row&7) on ds_read; inverse pre-applied on
// the per-lane global source of global_load_lds (rule 21, both-sides).
// vmcnt ledger: steady state each phase stages 2 loads; vmcnt(6) at phase p
// forces stage S(p-3) landed; every read consumes stages <= S(p-4). Final
// iteration is peeled with drain waits {6,6,4,2,2,0,-,-} (the round-2 race:
// vmcnt(6) with <8 outstanding is a no-op).
template <int EPI>
__global__ __launch_bounds__(512, 2) void gemm8_kernel(
    const u16* __restrict__ Ab, const u16* __restrict__ Bb,
    void* __restrict__ Cout,
    const float* __restrict__ aux1, const float* __restrict__ aux2,
    int M, int Nc, int K,
    long sA, long sB, long sC, long sAux1, float scale) {
  __shared__ u16 lds[65536];

  int nwg = gridDim.x;
  int orig = blockIdx.x;
  int swz = (orig & 7) * (nwg >> 3) + (orig >> 3);
  int gxm = M >> 8, gyn = Nc >> 8;
  int pb = gxm * gyn;
  int bz = swz / pb;
  int rem = swz - bz * pb;
  int by = rem / gxm;
  int bx = rem - by * gxm;
  int m0 = bx << 8, n0 = by << 8;

  const u16* Ap = Ab + (size_t)bz * sA;
  const u16* Bp = Bb + (size_t)bz * sB;

  int t = threadIdx.x, wid = t >> 6, l = t & 63;
  int wr = wid >> 2, wc = wid & 3;
  int sr = l >> 3;                  // staging row-in-8
  int scb = ((l & 7) ^ sr) * 8;     // staging source chunk (inverse swizzle)
  int frow = l & 15, fq = l >> 4, fx = l & 7;

  auto stA = [&](int tile, int h) {
    int slot = tile & 1;
    const u16* g = Ap + (size_t)(m0 + h * 128 + wid * 16 + sr) * K + tile * 64 + scb;
    u16* lb = &lds[slot * 16384 + h * 8192 + wid * 1024];
    load_lds16(g, lb);
    load_lds16(g + (size_t)8 * K, lb + 512);
  };
  auto stB = [&](int tile, int h) {
    int slot = tile & 1;
    const u16* g = Bp + (size_t)(n0 + h * 128 + wid * 16 + sr) * K + tile * 64 + scb;
    u16* lb = &lds[32768 + slot * 16384 + h * 8192 + wid * 1024];
    load_lds16(g, lb);
    load_lds16(g + (size_t)8 * K, lb + 512);
  };

  s16x8 af[4][2], bf[2][2];
  auto rdA = [&](int slot, int h) {
    const u16* base = &lds[slot * 16384 + h * 8192];
#pragma unroll
    for (int m = 0; m < 4; m++) {
      int row = wr * 64 + m * 16 + frow;
#pragma unroll
      for (int kk = 0; kk < 2; kk++) {
        int ch = (kk * 4 + fq) ^ fx;
        af[m][kk] = *(const s16x8*)&base[row * 64 + ch * 8];
      }
    }
  };
  auto rdB = [&](int slot, int h) {
    const u16* base = &lds[32768 + slot * 16384 + h * 8192];
#pragma unroll
    for (int n = 0; n < 2; n++) {
      int row = wc * 32 + n * 16 + frow;
#pragma unroll
      for (int kk = 0; kk < 2; kk++) {
        int ch = (kk * 4 + fq) ^ fx;
        bf[n][kk] = *(const s16x8*)&base[row * 64 + ch * 8];
      }
    }
  };

  f32x4 acc[2][2][4][2];
#pragma unroll
  for (int a = 0; a < 2; a++)
#pragma unroll
    for (int b = 0; b < 2; b++)
#pragma unroll
      for (int m = 0; m < 4; m++)
#pragma unroll
        for (int n = 0; n < 2; n++) acc[a][b][m][n] = (f32x4){0.f, 0.f, 0.f, 0.f};

#define MFMA_Q(QM, QN)                                                        \
  do {                                                                        \
    __builtin_amdgcn_s_setprio(1);                                            \
    _Pragma("unroll") for (int m = 0; m < 4; m++)                             \
        _Pragma("unroll") for (int n = 0; n < 2; n++)                         \
        _Pragma("unroll") for (int kk = 0; kk < 2; kk++)                      \
            acc[QM][QN][m][n] = __builtin_amdgcn_mfma_f32_16x16x32_bf16(      \
                af[m][kk], bf[n][kk], acc[QM][QN][m][n], 0, 0, 0);            \
    __builtin_amdgcn_s_setprio(0);                                            \
  } while (0)

  // prologue
  stA(0, 0); stB(0, 1); stB(0, 0); stA(0, 1); stA(1, 0); stB(1, 1);
  BAR_VM4();  // tile0 fully landed; tile1 A0/B1 in flight

  int nt = K >> 6, niter = nt >> 1;
  // main loop: all iterations except the last (stages always in-bounds)
  for (int i = 0; i < niter - 1; i++) {
    int t0 = 2 * i;
    rdA(0, 0); rdB(0, 0);
    stB(t0 + 1, 0);
    BAR_VM6(); MFMA_Q(0, 0); BAR_PLAIN();
    rdB(0, 1);
    stA(t0 + 1, 1);
    BAR_VM6(); MFMA_Q(0, 1); BAR_PLAIN();
    rdA(0, 1);
    stA(t0 + 2, 0);
    BAR_VM6(); MFMA_Q(1, 1); BAR_PLAIN();
    rdB(0, 0);
    stB(t0 + 2, 1);
    BAR_VM6(); MFMA_Q(1, 0); BAR_PLAIN();
    rdA(1, 0); rdB(1, 0);
    stB(t0 + 2, 0);
    BAR_VM6(); MFMA_Q(0, 0); BAR_PLAIN();
    rdB(1, 1);
    stA(t0 + 2, 1);
    BAR_VM6(); MFMA_Q(0, 1); BAR_PLAIN();
    rdA(1, 1);
    stA(t0 + 3, 0);
    BAR_VM6(); MFMA_Q(1, 1); BAR_PLAIN();
    rdB(1, 0);
    stB(t0 + 3, 1);
    BAR_VM6(); MFMA_Q(1, 0); BAR_PLAIN();
  }
  // peeled final iteration: tiles nt-2 (slot0), nt-1 (slot1); drain vmcnt.
  {
    int t0 = nt - 2;
    rdA(0, 0); rdB(0, 0);
    stB(t0 + 1, 0);
    BAR_VM6(); MFMA_Q(0, 0); BAR_PLAIN();   // forces prev ph6 stage (A t0,h1)
    rdB(0, 1);
    stA(t0 + 1, 1);
    BAR_VM6(); MFMA_Q(0, 1); BAR_PLAIN();   // forces prev ph7 stage (A t0+1,h0)
    rdA(0, 1);
    BAR_VM4(); MFMA_Q(1, 1); BAR_PLAIN();   // forces prev ph8 stage (B t0+1,h1)
    rdB(0, 0);
    BAR_VM2(); MFMA_Q(1, 0); BAR_PLAIN();   // forces e-ph1 stage (B t0+1,h0)
    rdA(1, 0); rdB(1, 0);
    BAR_VM2(); MFMA_Q(0, 0); BAR_PLAIN();   // no-op wait
    rdB(1, 1);
    BAR_VM0(); MFMA_Q(0, 1); BAR_PLAIN();   // forces e-ph2 stage (A t0+1,h1)
    rdA(1, 1);
    BAR_PLAIN(); MFMA_Q(1, 1); BAR_PLAIN(); // all landed
    rdB(1, 0);
    BAR_PLAIN(); MFMA_Q(1, 0);              // last phase: no trailing barrier needed
  }
#undef MFMA_Q

  // epilogue
#pragma unroll
  for (int qm = 0; qm < 2; qm++) {
#pragma unroll
    for (int qn = 0; qn < 2; qn++) {
#pragma unroll
      for (int m = 0; m < 4; m++) {
#pragma unroll
        for (int n = 0; n < 2; n++) {
#pragma unroll
          for (int r = 0; r < 4; r++) {
            int grow = m0 + qm * 128 + wr * 64 + m * 16 + fq * 4 + r;
            int gcol = n0 + qn * 128 + wc * 32 + n * 16 + frow;
            float a = acc[qm][qn][m][n][r];
            size_t ci = (size_t)grow * Nc + gcol;
            if (EPI == 0) {
              ((u16*)Cout)[(size_t)bz * sC + ci] = f2bf(a * scale);
            } else if (EPI == 1) {
              float vv = aux1[(size_t)bz * sAux1 + ci];
              ((u16*)Cout)[(size_t)bz * sC + ci] = f2bf(vv - a);
            } else if (EPI == 2) {
              ((float*)Cout)[ci] = a + aux2[gcol] + aux1[ci];
            } else {
              float x = a + aux2[gcol];
              float gl = 0.5f * x * (1.0f + erff(x * 0.70710678118654752f));
              ((u16*)Cout)[ci] = f2bf(gl);
            }
          }
        }
      }
    }
  }
}

// ------------------------- launch -------------------------

extern "C" void kernel_launch(void* const* d_in, const int* in_sizes, int n_in,
                              void* d_out, int out_size, void* d_ws, size_t ws_size,
                              hipStream_t stream) {
  const float* q      = (const float*)d_in[0];
  const float* k      = (const float*)d_in[1];
  const float* v      = (const float*)d_in[2];
  const float* W_diff = (const float*)d_in[3];
  const float* b_diff = (const float*)d_in[4];
  const float* ln_g   = (const float*)d_in[5];
  const float* ln_b   = (const float*)d_in[6];
  const float* W1     = (const float*)d_in[7];
  const float* b1     = (const float*)d_in[8];
  const float* W2     = (const float*)d_in[9];
  const float* b2     = (const float*)d_in[10];

  const int B = 8, N = 2048, D = 1024, H = 4096;
  char* ws = (char*)d_ws;
  u16* A   = (u16*)(ws + 0);            // 33.5M
  u16* Bm  = (u16*)(ws + 33554432);     // 33.5M
  u16* X   = (u16*)(ws + 33554432);     // reuses Bm after GEMM1
  u16* Vt  = (u16*)(ws + 67108864);     // 33.5M
  u16* S   = (u16*)(ws + 100663296);    // 67M
  u16* Hbf = (u16*)(ws + 134217728);    // 33.5M
  u16* Wd  = (u16*)(ws + 167772160);    // 2M
  u16* W1b = (u16*)(ws + 169869312);    // 8M
  u16* W2b = (u16*)(ws + 178257920);    // 8M
  u16* G   = (u16*)(ws + 0);            // 134M, aliases A/X/Vt/S-low
  float* out = (float*)d_out;

  cast_bf4_kernel<<<(D * D / 4) / 256, 256, 0, stream>>>(W_diff, Wd, D * D / 4);
  cast_bf4_kernel<<<(H * D / 4) / 256, 256, 0, stream>>>(W1, W1b, H * D / 4);
  cast_bf4_kernel<<<(D * H / 4) / 256, 256, 0, stream>>>(W2, W2b, D * H / 4);

  prob_kernel<<<B * N, 256, 0, stream>>>(q, k, A, Bm);
  transpose_v_kernel<<<dim3(D / 32, N / 32, B), 256, 0, stream>>>(v, Vt);

  // GEMM1: S = bf16(-(A @ Bm^T)/32)   [8x(2048x2048x1024)] grid 512
  gemm8_kernel<0><<<8 * 8 * 8, 512, 0, stream>>>(
      A, Bm, S, nullptr, nullptr, N, N, D,
      (long)N * D, (long)N * D, (long)N * N, 0, -0.03125f);

  softmax_rows_kernel<<<B * N, 256, 0, stream>>>(S);

  // GEMM2: X = bf16(v - attn @ v)     [8x(2048x1024x2048)] grid 256
  gemm8_kernel<1><<<8 * 4 * 8, 512, 0, stream>>>(
      S, Vt, X, v, nullptr, N, D, N,
      (long)N * N, (long)D * N, (long)N * D, (long)N * D, 1.0f);

  // GEMM3: f_diff = X @ Wd^T + b_diff + q -> d_out f32  [16384x1024x1024] grid 256
  gemm8_kernel<2><<<64 * 4, 512, 0, stream>>>(
      X, Wd, out, q, b_diff, B * N, D, D, 0, 0, 0, 0, 1.0f);

  layernorm_rows_kernel<1><<<B * N, 256, 0, stream>>>(out, Hbf, ln_g, ln_b);

  // GEMM4: G = bf16(gelu(h @ W1^T + b1))  [16384x4096x1024] grid 1024
  gemm8_kernel<3><<<64 * 16, 512, 0, stream>>>(
      Hbf, W1b, G, nullptr, b1, B * N, H, D, 0, 0, 0, 0, 1.0f);

  // GEMM5: out = G @ W2^T + b2 + f_diff   [16384x1024x4096] grid 256
  gemm8_kernel<2><<<64 * 4, 512, 0, stream>>>(
      G, W2b, out, out, b2, B * N, D, H, 0, 0, 0, 0, 1.0f);

  layernorm_rows_kernel<0><<<B * N, 256, 0, stream>>>(out, out, ln_g, ln_b);
}

// Round 4
// 604.304 us; speedup vs baseline: 1.5426x; 1.0881x over previous
//
#include <hip/hip_runtime.h>
#include <math.h>

typedef unsigned short u16;
typedef __attribute__((ext_vector_type(4))) unsigned short u16x4;
typedef __attribute__((ext_vector_type(8))) short s16x8;
typedef __attribute__((ext_vector_type(4))) float f32x4;
typedef __attribute__((ext_vector_type(4))) float f4v;

#define DEVI static __device__ __forceinline__

DEVI u16 f2bf(float f) {
  union { float f; unsigned u; } c; c.f = f;
  return (u16)((c.u + 0x7FFFu + ((c.u >> 16) & 1u)) >> 16);
}
DEVI float bf2f(u16 h) {
  union { unsigned u; float f; } c; c.u = ((unsigned)h) << 16;
  return c.f;
}

DEVI float tanh_fast(float x) {          // branch-free: 1-2/(e^{2x}+1)
  float e = __expf(2.0f * x);            // v_mul + v_exp_f32; inf-safe
  float r = __builtin_amdgcn_rcpf(e + 1.0f);
  return fmaf(-2.0f, r, 1.0f);
}
DEVI float gelu_fast(float x) {          // tanh-form gelu, ~9 VALU ops
  float x2 = x * x;
  float u = x * fmaf(x2, 0.0356774081f, 0.7978845608f);
  float e = __expf(2.0f * u);
  float r = __builtin_amdgcn_rcpf(e + 1.0f);
  float t = fmaf(-2.0f, r, 1.0f);
  float hx = 0.5f * x;
  return fmaf(hx, t, hx);
}

DEVI void load_lds16(const void* g, void* l) {
  __builtin_amdgcn_global_load_lds(
      (const __attribute__((address_space(1))) void*)g,
      (__attribute__((address_space(3))) void*)l, 16, 0, 0);
}

#define BAR_VM6() asm volatile("s_waitcnt vmcnt(6)\n\ts_barrier" ::: "memory")
#define BAR_VM4() asm volatile("s_waitcnt vmcnt(4)\n\ts_barrier" ::: "memory")
#define BAR_VM2() asm volatile("s_waitcnt vmcnt(2)\n\ts_barrier" ::: "memory")
#define BAR_VM0() asm volatile("s_waitcnt vmcnt(0)\n\ts_barrier" ::: "memory")
#define BAR_PLAIN() asm volatile("s_barrier" ::: "memory")

// ------------------------- small kernels -------------------------

__global__ __launch_bounds__(256) void cast_bf4_kernel(
    const float* __restrict__ in, u16* __restrict__ out, int n4) {
  int i = blockIdx.x * 256 + threadIdx.x;
  if (i >= n4) return;
  f4v f = ((const f4v*)in)[i];
  u16x4 o;
  o[0] = f2bf(f[0]); o[1] = f2bf(f[1]); o[2] = f2bf(f[2]); o[3] = f2bf(f[3]);
  ((u16x4*)out)[i] = o;
}

__global__ __launch_bounds__(256) void prob_kernel(
    const float* __restrict__ q, const float* __restrict__ k,
    u16* __restrict__ A, u16* __restrict__ Bm) {
  const int D = 1024;
  size_t row = blockIdx.x;
  int t = threadIdx.x;
  f4v qv = ((const f4v*)(q + row * D))[t];
  f4v kv = ((const f4v*)(k + row * D))[t];
  float tq[4], tk[4];
  float sq = 0.f, sk = 0.f;
#pragma unroll
  for (int i = 0; i < 4; i++) {
    tq[i] = tanh_fast(qv[i]) * 0.499f + 0.5f;
    tk[i] = tanh_fast(kv[i]) * 0.499f + 0.5f;
    sq += tq[i]; sk += tk[i];
  }
#pragma unroll
  for (int off = 32; off > 0; off >>= 1) {
    sq += __shfl_xor(sq, off);
    sk += __shfl_xor(sk, off);
  }
  __shared__ float sbq[4], sbk[4];
  int lane = t & 63, w = t >> 6;
  if (lane == 0) { sbq[w] = sq; sbk[w] = sk; }
  __syncthreads();
  sq = sbq[0] + sbq[1] + sbq[2] + sbq[3];
  sk = sbk[0] + sbk[1] + sbk[2] + sbk[3];
  float iq = 1.0f / (sq + 1e-8f), ik = 1.0f / (sk + 1e-8f);
  u16x4 av, bv;
#pragma unroll
  for (int i = 0; i < 4; i++) {
    float qp = fmaxf(tq[i] * iq, 1e-8f);
    float kp = fmaxf(tk[i] * ik, 1e-8f);
    av[i] = f2bf(qp - kp);
    bv[i] = f2bf(__logf(qp) - __logf(kp));
  }
  ((u16x4*)(A + row * D))[t] = av;
  ((u16x4*)(Bm + row * D))[t] = bv;
}

__global__ __launch_bounds__(256) void transpose_v_kernel(
    const float* __restrict__ v, u16* __restrict__ Vt) {
  const int N = 2048, D = 1024;
  __shared__ float tile[32][33];
  int b = blockIdx.z;
  int d0 = blockIdx.x * 32, n0 = blockIdx.y * 32;
  int tx = threadIdx.x & 31, ty = threadIdx.x >> 5;
  const float* vb = v + (size_t)b * N * D;
  u16* vtb = Vt + (size_t)b * N * D;
#pragma unroll
  for (int i = 0; i < 4; i++)
    tile[ty + i * 8][tx] = vb[(size_t)(n0 + ty + i * 8) * D + d0 + tx];
  __syncthreads();
#pragma unroll
  for (int i = 0; i < 4; i++)
    vtb[(size_t)(d0 + ty + i * 8) * N + n0 + tx] = f2bf(tile[tx][ty + i * 8]);
}

__global__ __launch_bounds__(256) void softmax_rows_kernel(u16* __restrict__ S) {
  const int NN = 2048;
  size_t row = blockIdx.x;
  u16* r = S + row * NN;
  int t = threadIdx.x;
  s16x8 vv = ((const s16x8*)r)[t];
  float x[8];
  float mx = -1e30f;
#pragma unroll
  for (int i = 0; i < 8; i++) { x[i] = bf2f((u16)vv[i]); mx = fmaxf(mx, x[i]); }
#pragma unroll
  for (int off = 32; off > 0; off >>= 1) mx = fmaxf(mx, __shfl_xor(mx, off));
  __shared__ float sm[4], ss[4];
  int lane = t & 63, w = t >> 6;
  if (lane == 0) sm[w] = mx;
  __syncthreads();
  mx = fmaxf(fmaxf(sm[0], sm[1]), fmaxf(sm[2], sm[3]));
  float sum = 0.f;
#pragma unroll
  for (int i = 0; i < 8; i++) { x[i] = __expf(x[i] - mx); sum += x[i]; }
#pragma unroll
  for (int off = 32; off > 0; off >>= 1) sum += __shfl_xor(sum, off);
  if (lane == 0) ss[w] = sum;
  __syncthreads();
  float inv = 1.0f / (ss[0] + ss[1] + ss[2] + ss[3]);
  s16x8 ov;
#pragma unroll
  for (int i = 0; i < 8; i++) ov[i] = (short)f2bf(x[i] * inv);
  ((s16x8*)r)[t] = ov;
}

template <int OUT_BF16>
__global__ __launch_bounds__(256) void layernorm_rows_kernel(
    const float* __restrict__ in, void* __restrict__ outp,
    const float* __restrict__ g, const float* __restrict__ bia) {
  const int D = 1024;
  size_t row = blockIdx.x;
  int t = threadIdx.x;
  f4v xv = ((const f4v*)(in + row * D))[t];
  float s = xv[0] + xv[1] + xv[2] + xv[3];
  float s2 = xv[0] * xv[0] + xv[1] * xv[1] + xv[2] * xv[2] + xv[3] * xv[3];
#pragma unroll
  for (int off = 32; off > 0; off >>= 1) {
    s += __shfl_xor(s, off);
    s2 += __shfl_xor(s2, off);
  }
  __shared__ float sa[4], sb[4];
  int lane = t & 63, w = t >> 6;
  if (lane == 0) { sa[w] = s; sb[w] = s2; }
  __syncthreads();
  s = sa[0] + sa[1] + sa[2] + sa[3];
  s2 = sb[0] + sb[1] + sb[2] + sb[3];
  float mean = s * (1.0f / D);
  float var = s2 * (1.0f / D) - mean * mean;
  float rs = rsqrtf(var + 1e-5f);
  f4v gv = ((const f4v*)g)[t];
  f4v bv = ((const f4v*)bia)[t];
  float y[4];
#pragma unroll
  for (int i = 0; i < 4; i++) y[i] = (xv[i] - mean) * rs * gv[i] + bv[i];
  if (OUT_BF16) {
    u16x4 o; o[0] = f2bf(y[0]); o[1] = f2bf(y[1]); o[2] = f2bf(y[2]); o[3] = f2bf(y[3]);
    ((u16x4*)outp)[row * (D / 4) + t] = o;
  } else {
    f4v o; o[0] = y[0]; o[1] = y[1]; o[2] = y[2]; o[3] = y[3];
    ((f4v*)outp)[row * (D / 4) + t] = o;
  }
}

// --------------- 8-phase 256x256 NT GEMM (T1+T2+T3+T4+T5) ---------------
// Verified structure (round 3). vmcnt ledger: steady state stages 2/phase,
// vmcnt(6) at phase p forces stage S(p-3); peeled final iter drains
// {6,6,4,2,2,0,-,-}. Swizzle: chunk^(row&7) on ds_read, inverse on the
// global source of global_load_lds (both-sides, rule 21).
template <int EPI>
__global__ __launch_bounds__(512, 2) void gemm8_kernel(
    const u16* __restrict__ Ab, const u16* __restrict__ Bb,
    void* __restrict__ Cout,
    const float* __restrict__ aux1, const float* __restrict__ aux2,
    int M, int Nc, int K,
    long sA, long sB, long sC, long sAux1, float scale) {
  __shared__ u16 lds[65536];

  int nwg = gridDim.x;
  int orig = blockIdx.x;
  int swz = (orig & 7) * (nwg >> 3) + (orig >> 3);
  int gxm = M >> 8, gyn = Nc >> 8;
  int pb = gxm * gyn;
  int bz = swz / pb;
  int rem = swz - bz * pb;
  int by = rem / gxm;
  int bx = rem - by * gxm;
  int m0 = bx << 8, n0 = by << 8;

  const u16* Ap = Ab + (size_t)bz * sA;
  const u16* Bp = Bb + (size_t)bz * sB;

  int t = threadIdx.x, wid = t >> 6, l = t & 63;
  int wr = wid >> 2, wc = wid & 3;
  int sr = l >> 3;
  int scb = ((l & 7) ^ sr) * 8;
  int frow = l & 15, fq = l >> 4, fx = l & 7;

  auto stA = [&](int tile, int h) {
    int slot = tile & 1;
    const u16* g = Ap + (size_t)(m0 + h * 128 + wid * 16 + sr) * K + tile * 64 + scb;
    u16* lb = &lds[slot * 16384 + h * 8192 + wid * 1024];
    load_lds16(g, lb);
    load_lds16(g + (size_t)8 * K, lb + 512);
  };
  auto stB = [&](int tile, int h) {
    int slot = tile & 1;
    const u16* g = Bp + (size_t)(n0 + h * 128 + wid * 16 + sr) * K + tile * 64 + scb;
    u16* lb = &lds[32768 + slot * 16384 + h * 8192 + wid * 1024];
    load_lds16(g, lb);
    load_lds16(g + (size_t)8 * K, lb + 512);
  };

  s16x8 af[4][2], bf[2][2];
  auto rdA = [&](int slot, int h) {
    const u16* base = &lds[slot * 16384 + h * 8192];
#pragma unroll
    for (int m = 0; m < 4; m++) {
      int row = wr * 64 + m * 16 + frow;
#pragma unroll
      for (int kk = 0; kk < 2; kk++) {
        int ch = (kk * 4 + fq) ^ fx;
        af[m][kk] = *(const s16x8*)&base[row * 64 + ch * 8];
      }
    }
  };
  auto rdB = [&](int slot, int h) {
    const u16* base = &lds[32768 + slot * 16384 + h * 8192];
#pragma unroll
    for (int n = 0; n < 2; n++) {
      int row = wc * 32 + n * 16 + frow;
#pragma unroll
      for (int kk = 0; kk < 2; kk++) {
        int ch = (kk * 4 + fq) ^ fx;
        bf[n][kk] = *(const s16x8*)&base[row * 64 + ch * 8];
      }
    }
  };

  f32x4 acc[2][2][4][2];
#pragma unroll
  for (int a = 0; a < 2; a++)
#pragma unroll
    for (int b = 0; b < 2; b++)
#pragma unroll
      for (int m = 0; m < 4; m++)
#pragma unroll
        for (int n = 0; n < 2; n++) acc[a][b][m][n] = (f32x4){0.f, 0.f, 0.f, 0.f};

#define MFMA_Q(QM, QN)                                                        \
  do {                                                                        \
    __builtin_amdgcn_s_setprio(1);                                            \
    _Pragma("unroll") for (int m = 0; m < 4; m++)                             \
        _Pragma("unroll") for (int n = 0; n < 2; n++)                         \
        _Pragma("unroll") for (int kk = 0; kk < 2; kk++)                      \
            acc[QM][QN][m][n] = __builtin_amdgcn_mfma_f32_16x16x32_bf16(      \
                af[m][kk], bf[n][kk], acc[QM][QN][m][n], 0, 0, 0);            \
    __builtin_amdgcn_s_setprio(0);                                            \
  } while (0)

  // prologue
  stA(0, 0); stB(0, 1); stB(0, 0); stA(0, 1); stA(1, 0); stB(1, 1);
  BAR_VM4();

  int nt = K >> 6, niter = nt >> 1;
  for (int i = 0; i < niter - 1; i++) {
    int t0 = 2 * i;
    rdA(0, 0); rdB(0, 0);
    stB(t0 + 1, 0);
    BAR_VM6(); MFMA_Q(0, 0); BAR_PLAIN();
    rdB(0, 1);
    stA(t0 + 1, 1);
    BAR_VM6(); MFMA_Q(0, 1); BAR_PLAIN();
    rdA(0, 1);
    stA(t0 + 2, 0);
    BAR_VM6(); MFMA_Q(1, 1); BAR_PLAIN();
    rdB(0, 0);
    stB(t0 + 2, 1);
    BAR_VM6(); MFMA_Q(1, 0); BAR_PLAIN();
    rdA(1, 0); rdB(1, 0);
    stB(t0 + 2, 0);
    BAR_VM6(); MFMA_Q(0, 0); BAR_PLAIN();
    rdB(1, 1);
    stA(t0 + 2, 1);
    BAR_VM6(); MFMA_Q(0, 1); BAR_PLAIN();
    rdA(1, 1);
    stA(t0 + 3, 0);
    BAR_VM6(); MFMA_Q(1, 1); BAR_PLAIN();
    rdB(1, 0);
    stB(t0 + 3, 1);
    BAR_VM6(); MFMA_Q(1, 0); BAR_PLAIN();
  }
  // peeled final iteration with drain ledger
  {
    int t0 = nt - 2;
    rdA(0, 0); rdB(0, 0);
    stB(t0 + 1, 0);
    BAR_VM6(); MFMA_Q(0, 0); BAR_PLAIN();
    rdB(0, 1);
    stA(t0 + 1, 1);
    BAR_VM6(); MFMA_Q(0, 1); BAR_PLAIN();
    rdA(0, 1);
    BAR_VM4(); MFMA_Q(1, 1); BAR_PLAIN();
    rdB(0, 0);
    BAR_VM2(); MFMA_Q(1, 0); BAR_PLAIN();
    rdA(1, 0); rdB(1, 0);
    BAR_VM2(); MFMA_Q(0, 0); BAR_PLAIN();
    rdB(1, 1);
    BAR_VM0(); MFMA_Q(0, 1); BAR_PLAIN();
    rdA(1, 1);
    BAR_PLAIN(); MFMA_Q(1, 1); BAR_PLAIN();
    rdB(1, 0);
    BAR_PLAIN(); MFMA_Q(1, 0);
  }
#undef MFMA_Q

  // epilogue
#pragma unroll
  for (int qm = 0; qm < 2; qm++) {
#pragma unroll
    for (int qn = 0; qn < 2; qn++) {
#pragma unroll
      for (int m = 0; m < 4; m++) {
#pragma unroll
        for (int n = 0; n < 2; n++) {
#pragma unroll
          for (int r = 0; r < 4; r++) {
            int grow = m0 + qm * 128 + wr * 64 + m * 16 + fq * 4 + r;
            int gcol = n0 + qn * 128 + wc * 32 + n * 16 + frow;
            float a = acc[qm][qn][m][n][r];
            size_t ci = (size_t)grow * Nc + gcol;
            if (EPI == 0) {
              ((u16*)Cout)[(size_t)bz * sC + ci] = f2bf(a * scale);
            } else if (EPI == 1) {
              float vv = aux1[(size_t)bz * sAux1 + ci];
              ((u16*)Cout)[(size_t)bz * sC + ci] = f2bf(vv - a);
            } else if (EPI == 2) {
              ((float*)Cout)[ci] = a + aux2[gcol] + aux1[ci];
            } else {
              ((u16*)Cout)[ci] = f2bf(gelu_fast(a + aux2[gcol]));
            }
          }
        }
      }
    }
  }
}

// ------------------------- launch -------------------------

extern "C" void kernel_launch(void* const* d_in, const int* in_sizes, int n_in,
                              void* d_out, int out_size, void* d_ws, size_t ws_size,
                              hipStream_t stream) {
  const float* q      = (const float*)d_in[0];
  const float* k      = (const float*)d_in[1];
  const float* v      = (const float*)d_in[2];
  const float* W_diff = (const float*)d_in[3];
  const float* b_diff = (const float*)d_in[4];
  const float* ln_g   = (const float*)d_in[5];
  const float* ln_b   = (const float*)d_in[6];
  const float* W1     = (const float*)d_in[7];
  const float* b1     = (const float*)d_in[8];
  const float* W2     = (const float*)d_in[9];
  const float* b2     = (const float*)d_in[10];

  const int B = 8, N = 2048, D = 1024, H = 4096;
  char* ws = (char*)d_ws;
  u16* A   = (u16*)(ws + 0);
  u16* Bm  = (u16*)(ws + 33554432);
  u16* X   = (u16*)(ws + 33554432);
  u16* Vt  = (u16*)(ws + 67108864);
  u16* S   = (u16*)(ws + 100663296);
  u16* Hbf = (u16*)(ws + 134217728);
  u16* Wd  = (u16*)(ws + 167772160);
  u16* W1b = (u16*)(ws + 169869312);
  u16* W2b = (u16*)(ws + 178257920);
  u16* G   = (u16*)(ws + 0);
  float* out = (float*)d_out;

  cast_bf4_kernel<<<(D * D / 4) / 256, 256, 0, stream>>>(W_diff, Wd, D * D / 4);
  cast_bf4_kernel<<<(H * D / 4) / 256, 256, 0, stream>>>(W1, W1b, H * D / 4);
  cast_bf4_kernel<<<(D * H / 4) / 256, 256, 0, stream>>>(W2, W2b, D * H / 4);

  prob_kernel<<<B * N, 256, 0, stream>>>(q, k, A, Bm);
  transpose_v_kernel<<<dim3(D / 32, N / 32, B), 256, 0, stream>>>(v, Vt);

  gemm8_kernel<0><<<8 * 8 * 8, 512, 0, stream>>>(
      A, Bm, S, nullptr, nullptr, N, N, D,
      (long)N * D, (long)N * D, (long)N * N, 0, -0.03125f);

  softmax_rows_kernel<<<B * N, 256, 0, stream>>>(S);

  gemm8_kernel<1><<<8 * 4 * 8, 512, 0, stream>>>(
      S, Vt, X, v, nullptr, N, D, N,
      (long)N * N, (long)D * N, (long)N * D, (long)N * D, 1.0f);

  gemm8_kernel<2><<<64 * 4, 512, 0, stream>>>(
      X, Wd, out, q, b_diff, B * N, D, D, 0, 0, 0, 0, 1.0f);

  layernorm_rows_kernel<1><<<B * N, 256, 0, stream>>>(out, Hbf, ln_g, ln_b);

  gemm8_kernel<3><<<64 * 16, 512, 0, stream>>>(
      Hbf, W1b, G, nullptr, b1, B * N, H, D, 0, 0, 0, 0, 1.0f);

  gemm8_kernel<2><<<64 * 4, 512, 0, stream>>>(
      G, W2b, out, out, b2, B * N, D, H, 0, 0, 0, 0, 1.0f);

  layernorm_rows_kernel<0><<<B * N, 256, 0, stream>>>(out, out, ln_g, ln_b);
}